// Round 8
// baseline (58.761 us; speedup 1.0000x reference)
//
#include <hip/hip_runtime.h>
#include <math.h>

#define BB 8
#define SS 64
#define NN 512
#define EE 32
#define IT 8

__device__ __forceinline__ unsigned short f2bf(float f) {
    union { float f; unsigned u; } v; v.f = f;
    unsigned r = v.u + 0x7fffu + ((v.u >> 16) & 1u);   // RTNE
    return (unsigned short)(r >> 16);
}

__device__ __forceinline__ float qsum(float v) {      // sum over 4-lane quad (VALU pipe)
    v += __int_as_float(__builtin_amdgcn_mov_dpp(__float_as_int(v), 0xB1, 0xF, 0xF, true));
    v += __int_as_float(__builtin_amdgcn_mov_dpp(__float_as_int(v), 0x4E, 0xF, 0xF, true));
    return v;
}

// proj: tip[b][e][n] = ti' = x^T W_i^T + b_w, tjp[b][e][n] = tj   (layout B,E,N)
//       cip[b][n] = sum_e Wa[e]*ti'[n][e];  djp[b][n] = sum_e Wa[e]*tj[n][e]
// 128 threads, n-tile 8, grid 512: 2 independent chains per CU.
__global__ __launch_bounds__(128) void proj_kernel(
    const float* __restrict__ x, const float* __restrict__ W,
    const float* __restrict__ b_w, const float* __restrict__ Wa,
    float* __restrict__ tip, float* __restrict__ tjp,
    float* __restrict__ cip, float* __restrict__ djp)
{
    __shared__ float sW[SS][65];
    const int t = threadIdx.x;
    const int wg = ((blockIdx.x & 7) << 6) | (blockIdx.x >> 3);  // XCD swizzle (512=8*64)
    const int b = wg >> 6;
    const int n0 = (wg & 63) << 3;

#pragma unroll
    for (int r = 0; r < 8; ++r) {   // stage W (4096 floats) as [s][eo]
        int idx = r * 512 + t * 4;
        float4 w4 = *(const float4*)(W + idx);
        int e = idx >> 7;
        int sp = idx & 127;
        int eo = ((sp >> 6) << 5) | e;   // 0..31 ti, 32..63 tj
        int s0 = sp & 63;
        sW[s0 + 0][eo] = w4.x;
        sW[s0 + 1][eo] = w4.y;
        sW[s0 + 2][eo] = w4.z;
        sW[s0 + 3][eo] = w4.w;
    }
    __syncthreads();

    const int eo = t & 63;               // lane (wave covers all 64 eo)
    const int ng = t >> 6;               // 0/1: n-quad
    const float* xb = x + (size_t)b * SS * NN + n0 + (ng << 2);
    float a0 = 0.f, a1 = 0.f, a2 = 0.f, a3 = 0.f;
#pragma unroll 8
    for (int s = 0; s < SS; ++s) {
        float wv = sW[s][eo];                               // conflict-free
        float4 xv = *(const float4*)(xb + (size_t)s * NN);  // wave-uniform bcast
        a0 = fmaf(wv, xv.x, a0);
        a1 = fmaf(wv, xv.y, a1);
        a2 = fmaf(wv, xv.z, a2);
        a3 = fmaf(wv, xv.w, a3);
    }
    const int e = eo & 31;
    const bool isI = eo < EE;
    float bias = isI ? b_w[e] : 0.f;
    a0 += bias; a1 += bias; a2 += bias; a3 += bias;
    float* dst = isI ? tip : tjp;
    *(float4*)(dst + ((size_t)(b * EE + e)) * NN + n0 + (ng << 2)) =
        make_float4(a0, a1, a2, a3);

    // rank-1 terms: reduce wa*val over each 32-lane half (xor<32 keeps halves apart)
    float wa = Wa[e];
    float r0 = wa * a0, r1 = wa * a1, r2 = wa * a2, r3 = wa * a3;
#pragma unroll
    for (int off = 1; off <= 16; off <<= 1) {
        r0 += __shfl_xor(r0, off);
        r1 += __shfl_xor(r1, off);
        r2 += __shfl_xor(r2, off);
        r3 += __shfl_xor(r3, off);
    }
    if (eo == 0)
        *(float4*)(cip + (size_t)b * NN + n0 + (ng << 2)) = make_float4(r0, r1, r2, r3);
    if (eo == 32)
        *(float4*)(djp + (size_t)b * NN + n0 + (ng << 2)) = make_float4(r0, r1, r2, r3);
}

// attn: block = (b, 8-i tile), 512 threads, target 64 VGPR -> 4 blocks/CU.
// PV is i-split into two passes so the live set fits 64 regs (R5 lesson:
// pacc[4][8]+psc[4][8] at once needs ~90 -> spills under the 64 cap).
__global__ __launch_bounds__(512, 4) void attn_kernel(
    const float* __restrict__ x,
    const float* __restrict__ tip,
    const float* __restrict__ tjp,
    const float* __restrict__ cip,
    const float* __restrict__ djp,
    const float* __restrict__ Wa,
    float* __restrict__ out0,
    float* __restrict__ out1)
{
    __shared__ __align__(16) unsigned scT[NN * 4];   // 8 KB: row j = 8 bf16 (i 0..7)
    __shared__ __align__(16) float hp[SS * 68];      // [s][w*8+i], s-stride 68 (17.4 KB)
    __shared__ __align__(16) float red[8][8];        // [wave][i] denom partials
    __shared__ float s_inv[IT];

    const int t = threadIdx.x;
    const int wg = ((blockIdx.x & 7) << 6) | (blockIdx.x >> 3);  // XCD swizzle (512=8*64)
    const int b = wg >> 6;
    const int i0 = (wg & 63) << 3;
    const int lane = t & 63;
    const int w = t >> 6;

    // ---- scores: thread owns j = t; ti/ci/Wa via scalar loads (SGPR operands) ----
    const float* tjb = tjp + (size_t)b * EE * NN + t;
    const float* tib = tip + (size_t)b * EE * NN + i0;   // block-uniform -> s_load
    float acc[IT];
#pragma unroll
    for (int i = 0; i < IT; ++i) acc[i] = 0.f;

#pragma unroll 8
    for (int e = 0; e < EE; ++e) {
        float tjv = tjb[(size_t)e * NN];                 // coalesced L2
        float wa = Wa[e];                                // uniform
#pragma unroll
        for (int i = 0; i < IT; ++i) {
            float p = tib[e * NN + i] + tjv;             // sgpr + vgpr
            acc[i] = fmaf(fabsf(p), wa, acc[i]);         // |p| input-modifier
        }
    }

    // epilogue: sc = 0.4*acc + 0.6*(ci + dj); no-max softmax (|sc| < ~10)
    float dj = djp[(size_t)b * NN + t];
    const float* cib = cip + (size_t)b * NN + i0;        // uniform
    float pr[IT];
#pragma unroll
    for (int i = 0; i < IT; ++i) {
        float sc = fmaf(0.4f, acc[i], 0.6f * (cib[i] + dj));
        pr[i] = __expf(sc);
    }

    // pack 8 bf16 (unnormalized) -> one 16B row of scT
    {
        unsigned p0 = f2bf(pr[0]) | ((unsigned)f2bf(pr[1]) << 16);
        unsigned p1 = f2bf(pr[2]) | ((unsigned)f2bf(pr[3]) << 16);
        unsigned p2 = f2bf(pr[4]) | ((unsigned)f2bf(pr[5]) << 16);
        unsigned p3 = f2bf(pr[6]) | ((unsigned)f2bf(pr[7]) << 16);
        uint4 pk; pk.x = p0; pk.y = p1; pk.z = p2; pk.w = p3;
        *(uint4*)&scT[t << 2] = pk;
    }

    // ---- softmax denominators: exact fp32 butterfly + cross-wave combine ----
    float rs[IT];
#pragma unroll
    for (int i = 0; i < IT; ++i) rs[i] = pr[i];
#pragma unroll
    for (int off = 1; off <= 32; off <<= 1) {
#pragma unroll
        for (int i = 0; i < IT; ++i) rs[i] += __shfl_xor(rs[i], off);
    }
    if (lane == 0) {
        *(float4*)&red[w][0] = make_float4(rs[0], rs[1], rs[2], rs[3]);
        *(float4*)&red[w][4] = make_float4(rs[4], rs[5], rs[6], rs[7]);
    }
    __syncthreads();
    if (t < IT) {
        float S = 0.f;
#pragma unroll
        for (int ww = 0; ww < 8; ++ww) S += red[ww][t];
        s_inv[t] = 1.0f / S;
    }
    __syncthreads();                                     // s_inv + scT visible

    // ---- attention rows from fp32 pr (coalesced 2KB per i-row); pr dies here ----
#pragma unroll
    for (int i = 0; i < IT; ++i)
        out1[((size_t)(b * NN + i0 + i)) * NN + t] = pr[i] * s_inv[i];

    // ---- PV: wave w owns j in [w*64,w*64+64); lane=(jw,sh); two i-half passes ----
    const int jw = t & 3;
    const int sh = (t >> 2) & 15;
    const float* xb = x + (size_t)b * SS * NN;

#pragma unroll 1
    for (int p = 0; p < 2; ++p) {                        // i-half: 4*p .. 4*p+3
        float pacc[4][4];
#pragma unroll
        for (int r = 0; r < 4; ++r)
#pragma unroll
            for (int i = 0; i < 4; ++i) pacc[r][i] = 0.f;

#pragma unroll
        for (int c4 = 0; c4 < 4; ++c4) {
            const int jseg = (w << 6) + (c4 << 4) + (jw << 2);
            float psc[4][4];
#pragma unroll
            for (int v = 0; v < 4; ++v) {                // b64 half-row, bcast x16
                uint2 d = *(const uint2*)((const unsigned char*)scT +
                                          (((jseg + v) << 4) | (p << 3)));
                psc[v][0] = __uint_as_float(d.x << 16);
                psc[v][1] = __uint_as_float(d.x & 0xffff0000u);
                psc[v][2] = __uint_as_float(d.y << 16);
                psc[v][3] = __uint_as_float(d.y & 0xffff0000u);
            }
#pragma unroll
            for (int r = 0; r < 4; ++r) {
                int s = (sh << 2) + r;
                float4 xv = *(const float4*)(xb + (size_t)s * NN + jseg);  // L2
#pragma unroll
                for (int i = 0; i < 4; ++i) {
                    float a = fmaf(xv.x, psc[0][i], pacc[r][i]);
                    a = fmaf(xv.y, psc[1][i], a);
                    a = fmaf(xv.z, psc[2][i], a);
                    pacc[r][i] = fmaf(xv.w, psc[3][i], a);
                }
            }
        }

        // 4-lane jw reduction on VALU pipe
#pragma unroll
        for (int r = 0; r < 4; ++r)
#pragma unroll
            for (int i = 0; i < 4; ++i) pacc[r][i] = qsum(pacc[r][i]);

        if (jw == 0) {
#pragma unroll
            for (int r = 0; r < 4; ++r) {
                int s = (sh << 2) + r;
                *(float4*)&hp[s * 68 + (w << 3) + (p << 2)] =
                    make_float4(pacc[r][0], pacc[r][1], pacc[r][2], pacc[r][3]);
            }
        }
    }
    __syncthreads();

    // ---- h: combine 8 wave-partials, scale by inv, sigmoid ----
    {
        int s = t >> 3, ip = t & 7;
        float h = 0.f;
#pragma unroll
        for (int ww = 0; ww < 8; ++ww) h += hp[s * 68 + (ww << 3) + ip];
        h *= s_inv[ip];
        out0[((size_t)(b * SS + s)) * NN + i0 + ip] = 1.0f / (1.0f + __expf(-h));
    }
}

extern "C" void kernel_launch(void* const* d_in, const int* in_sizes, int n_in,
                              void* d_out, int out_size, void* d_ws, size_t ws_size,
                              hipStream_t stream) {
    const float* x   = (const float*)d_in[0];
    const float* W   = (const float*)d_in[1];
    const float* b_w = (const float*)d_in[2];
    const float* Wa  = (const float*)d_in[3];

    float* out0 = (float*)d_out;                         // (B,S,N)
    float* out1 = (float*)d_out + (size_t)BB * SS * NN;  // (B,N,N)

    float* tip = (float*)d_ws;                           // (B,E,N)
    float* tjp = tip + (size_t)BB * EE * NN;             // (B,E,N)
    float* cip = tjp + (size_t)BB * EE * NN;             // (B,N)
    float* djp = cip + (size_t)BB * NN;                  // (B,N)

    proj_kernel<<<BB * (NN / 8), 128, 0, stream>>>(x, W, b_w, Wa, tip, tjp, cip, djp);
    attn_kernel<<<BB * (NN / IT), 512, 0, stream>>>(x, tip, tjp, cip, djp, Wa, out0, out1);
}

// Round 9
// 22.222 us; speedup vs baseline: 2.6443x; 2.6443x over previous
//
#include <hip/hip_runtime.h>
#include <math.h>

#define BB 8
#define SS 64
#define NN 512
#define EE 32
#define IT 16

__device__ __forceinline__ unsigned short f2bf(float f) {
    union { float f; unsigned u; } v; v.f = f;
    unsigned r = v.u + 0x7fffu + ((v.u >> 16) & 1u);   // RTNE
    return (unsigned short)(r >> 16);
}
__device__ __forceinline__ float bflo(unsigned u) { return __uint_as_float(u << 16); }
__device__ __forceinline__ float bfhi(unsigned u) { return __uint_as_float(u & 0xffff0000u); }

__device__ __forceinline__ float qsum(float v) {      // sum over 4-lane quad (VALU pipe)
    v += __int_as_float(__builtin_amdgcn_mov_dpp(__float_as_int(v), 0xB1, 0xF, 0xF, true));
    v += __int_as_float(__builtin_amdgcn_mov_dpp(__float_as_int(v), 0x4E, 0xF, 0xF, true));
    return v;
}

// proj: tip[b][e][n] fp32 = ti'+b_w; tjb[b][e][n] bf16-packed = tj  (layout B,E,N)
//       cip[b][n] = sum_e Wa[e]*ti'[n][e];  djp[b][n] = sum_e Wa[e]*tj[n][e]
__global__ __launch_bounds__(128) void proj_kernel(
    const float* __restrict__ x, const float* __restrict__ W,
    const float* __restrict__ b_w, const float* __restrict__ Wa,
    float* __restrict__ tip, unsigned short* __restrict__ tjb,
    float* __restrict__ cip, float* __restrict__ djp)
{
    __shared__ float sW[SS][65];
    const int t = threadIdx.x;
    const int wg = ((blockIdx.x & 7) << 6) | (blockIdx.x >> 3);  // XCD swizzle (512=8*64)
    const int b = wg >> 6;
    const int n0 = (wg & 63) << 3;

#pragma unroll
    for (int r = 0; r < 8; ++r) {   // stage W (4096 floats) as [s][eo]
        int idx = r * 512 + t * 4;
        float4 w4 = *(const float4*)(W + idx);
        int e = idx >> 7;
        int sp = idx & 127;
        int eo = ((sp >> 6) << 5) | e;   // 0..31 ti, 32..63 tj
        int s0 = sp & 63;
        sW[s0 + 0][eo] = w4.x;
        sW[s0 + 1][eo] = w4.y;
        sW[s0 + 2][eo] = w4.z;
        sW[s0 + 3][eo] = w4.w;
    }
    __syncthreads();

    const int eo = t & 63;
    const int ng = t >> 6;               // 0/1
    const float* xb = x + (size_t)b * SS * NN + n0 + (ng << 2);
    float a0 = 0.f, a1 = 0.f, a2 = 0.f, a3 = 0.f;
#pragma unroll 8
    for (int s = 0; s < SS; ++s) {
        float wv = sW[s][eo];                               // conflict-free
        float4 xv = *(const float4*)(xb + (size_t)s * NN);  // wave-uniform bcast
        a0 = fmaf(wv, xv.x, a0);
        a1 = fmaf(wv, xv.y, a1);
        a2 = fmaf(wv, xv.z, a2);
        a3 = fmaf(wv, xv.w, a3);
    }
    const int e = eo & 31;
    const bool isI = eo < EE;
    if (isI) {
        float bias = b_w[e];
        a0 += bias; a1 += bias; a2 += bias; a3 += bias;
        *(float4*)(tip + ((size_t)(b * EE + e)) * NN + n0 + (ng << 2)) =
            make_float4(a0, a1, a2, a3);
    } else {
        unsigned u0 = f2bf(a0) | ((unsigned)f2bf(a1) << 16);
        unsigned u1 = f2bf(a2) | ((unsigned)f2bf(a3) << 16);
        *(uint2*)(tjb + ((size_t)(b * EE + e)) * NN + n0 + (ng << 2)) =
            make_uint2(u0, u1);
    }

    // rank-1 terms: reduce wa*val over each 32-lane half (xor<32 keeps halves apart)
    float wa = Wa[e];
    float r0 = wa * a0, r1 = wa * a1, r2 = wa * a2, r3 = wa * a3;
#pragma unroll
    for (int off = 1; off <= 16; off <<= 1) {
        r0 += __shfl_xor(r0, off);
        r1 += __shfl_xor(r1, off);
        r2 += __shfl_xor(r2, off);
        r3 += __shfl_xor(r3, off);
    }
    if (eo == 0)
        *(float4*)(cip + (size_t)b * NN + n0 + (ng << 2)) = make_float4(r0, r1, r2, r3);
    if (eo == 32)
        *(float4*)(djp + (size_t)b * NN + n0 + (ng << 2)) = make_float4(r0, r1, r2, r3);
}

// attn: block = (b, 16-i tile), 512 threads, grid 256 (1 block/CU). LDS ~99KB.
// (512,2): 128-VGPR regime. NEVER (512,4): 64-cap => guaranteed spill (R5/R8).
__global__ __launch_bounds__(512, 2) void attn_kernel(
    const float* __restrict__ x,
    const float* __restrict__ tip,
    const unsigned short* __restrict__ tjb,
    const float* __restrict__ cip,
    const float* __restrict__ djp,
    const float* __restrict__ Wa,
    float* __restrict__ out0,
    float* __restrict__ out1)
{
    __shared__ __align__(16) unsigned short stj[EE * NN];  // 32KB bf16 tj
    __shared__ __align__(16) unsigned scT[NN * 12];        // 24KB: row j = 8 u32 (16 bf16) + 4 pad
    __shared__ __align__(16) float s_tiT[IT][36];          // [i][e] fp32
    __shared__ __align__(16) float hp[8 * SS * 20];        // 40KB PV partials [w8][s][20]
    __shared__ __align__(16) float red[8][IT];
    __shared__ float s_inv[IT];

    const int t = threadIdx.x;
    const int wg = ((blockIdx.x & 7) << 5) | (blockIdx.x >> 3);  // XCD swizzle (256=8*32)
    const int b = wg >> 5;
    const int i0 = (wg & 31) << 4;
    const int lane = t & 63;
    const int w = t >> 6;

    // ---- stage ti (fp32) and tj (bf16) ----
    {
        int i = t & 15, e = t >> 4;
        s_tiT[i][e] = tip[((size_t)(b * EE + e)) * NN + i0 + i];
    }
    {
        const uint4* src = (const uint4*)(tjb + (size_t)b * EE * NN);
        uint4* dst = (uint4*)stj;
#pragma unroll
        for (int r = 0; r < 4; ++r) dst[r * 512 + t] = src[r * 512 + t];
    }
    __syncthreads();

    // ---- scores: thread owns i in {2ip,2ip+1}, j in [jc*8, jc*8+8) ----
    const int ip = t & 7;
    const int jc = t >> 3;          // 0..63
    const int j0 = jc << 3;
    const int ia = 2 * ip, ib2 = 2 * ip + 1;

    float rti0[EE], rti1[EE];
#pragma unroll
    for (int q = 0; q < 8; ++q) {
        float4 v = *(const float4*)&s_tiT[ia][q << 2];
        rti0[4 * q + 0] = v.x; rti0[4 * q + 1] = v.y;
        rti0[4 * q + 2] = v.z; rti0[4 * q + 3] = v.w;
        float4 u = *(const float4*)&s_tiT[ib2][q << 2];
        rti1[4 * q + 0] = u.x; rti1[4 * q + 1] = u.y;
        rti1[4 * q + 2] = u.z; rti1[4 * q + 3] = u.w;
    }

    float acc0[8], acc1[8];
#pragma unroll
    for (int k = 0; k < 8; ++k) { acc0[k] = 0.f; acc1[k] = 0.f; }

#pragma unroll
    for (int e = 0; e < EE; ++e) {
        uint4 d = *(const uint4*)&stj[e * NN + j0];      // 8 bf16, conflict-free b128
        float wa = Wa[e];                                // uniform s_load
        float t0 = rti0[e], t1 = rti1[e];
        float tjf[8];
        tjf[0] = bflo(d.x); tjf[1] = bfhi(d.x);
        tjf[2] = bflo(d.y); tjf[3] = bfhi(d.y);
        tjf[4] = bflo(d.z); tjf[5] = bfhi(d.z);
        tjf[6] = bflo(d.w); tjf[7] = bfhi(d.w);
#pragma unroll
        for (int k = 0; k < 8; ++k) {
            acc0[k] = fmaf(fabsf(t0 + tjf[k]), wa, acc0[k]);   // |p| input-mod
            acc1[k] = fmaf(fabsf(t1 + tjf[k]), wa, acc1[k]);
        }
    }

    // epilogue: sc = 0.4*acc + 0.6*(ci + dj); no-max softmax (|sc| small, N(0,1) data)
    float dj8[8];
    {
        float4 d0 = *(const float4*)(djp + (size_t)b * NN + j0);
        float4 d1 = *(const float4*)(djp + (size_t)b * NN + j0 + 4);
        dj8[0] = d0.x; dj8[1] = d0.y; dj8[2] = d0.z; dj8[3] = d0.w;
        dj8[4] = d1.x; dj8[5] = d1.y; dj8[6] = d1.z; dj8[7] = d1.w;
    }
    float c0 = cip[(size_t)b * NN + i0 + ia];
    float c1 = cip[(size_t)b * NN + i0 + ib2];
    float pr0[8], pr1[8];
#pragma unroll
    for (int k = 0; k < 8; ++k) {
        pr0[k] = __expf(fmaf(0.4f, acc0[k], 0.6f * (c0 + dj8[k])));
        pr1[k] = __expf(fmaf(0.4f, acc1[k], 0.6f * (c1 + dj8[k])));
    }

    // write scT: row j, slot ip = bf16 pair (i=2ip, 2ip+1)
#pragma unroll
    for (int k = 0; k < 8; ++k) {
        scT[(j0 + k) * 12 + ip] = f2bf(pr0[k]) | ((unsigned)f2bf(pr1[k]) << 16);
    }

    // ---- softmax denominators: in-thread sum + jc-lane shuffle + cross-wave ----
    float rs0 = 0.f, rs1 = 0.f;
#pragma unroll
    for (int k = 0; k < 8; ++k) { rs0 += pr0[k]; rs1 += pr1[k]; }
#pragma unroll
    for (int off = 8; off <= 32; off <<= 1) {
        rs0 += __shfl_xor(rs0, off);
        rs1 += __shfl_xor(rs1, off);
    }
    if (lane < 8) { red[w][2 * lane] = rs0; red[w][2 * lane + 1] = rs1; }
    __syncthreads();
    if (t < IT) {
        float S = 0.f;
#pragma unroll
        for (int ww = 0; ww < 8; ++ww) S += red[ww][t];
        s_inv[t] = 1.0f / S;
    }
    __syncthreads();                                     // s_inv + scT visible

    // ---- attention rows (fp32 pr, coalesced 32B/thread) ----
    {
        float v0 = s_inv[ia], v1 = s_inv[ib2];
        float* r0p = out1 + ((size_t)(b * NN + i0 + ia)) * NN + j0;
        float* r1p = out1 + ((size_t)(b * NN + i0 + ib2)) * NN + j0;
        *(float4*)(r0p)     = make_float4(pr0[0]*v0, pr0[1]*v0, pr0[2]*v0, pr0[3]*v0);
        *(float4*)(r0p + 4) = make_float4(pr0[4]*v0, pr0[5]*v0, pr0[6]*v0, pr0[7]*v0);
        *(float4*)(r1p)     = make_float4(pr1[0]*v1, pr1[1]*v1, pr1[2]*v1, pr1[3]*v1);
        *(float4*)(r1p + 4) = make_float4(pr1[4]*v1, pr1[5]*v1, pr1[6]*v1, pr1[7]*v1);
    }

    // ---- PV: h[s][i] = sum_j pr[i][j]*x[b][s][j] ----
    const int jw = t & 3;
    const int sq = (t >> 2) & 7;
    const int ih = (t >> 5) & 1;
    const int w8 = t >> 6;
    float pacc[8][8];
#pragma unroll
    for (int r = 0; r < 8; ++r)
#pragma unroll
        for (int c = 0; c < 8; ++c) pacc[r][c] = 0.f;

    const float* xbb = x + (size_t)b * SS * NN;
#pragma unroll
    for (int uu = 0; uu < 4; ++uu) {
        const int jb = uu * 128 + w8 * 16 + jw * 4;
        float xq[8][4];
#pragma unroll
        for (int r = 0; r < 8; ++r) {
            float4 xv = *(const float4*)(xbb + (size_t)(sq + 8 * r) * NN + jb);
            xq[r][0] = xv.x; xq[r][1] = xv.y; xq[r][2] = xv.z; xq[r][3] = xv.w;
        }
#pragma unroll
        for (int v = 0; v < 4; ++v) {
            uint4 dd = *(const uint4*)&scT[(jb + v) * 12 + (ih << 2)];  // 2-way banks
            float ps[8];
            ps[0] = bflo(dd.x); ps[1] = bfhi(dd.x);
            ps[2] = bflo(dd.y); ps[3] = bfhi(dd.y);
            ps[4] = bflo(dd.z); ps[5] = bfhi(dd.z);
            ps[6] = bflo(dd.w); ps[7] = bfhi(dd.w);
#pragma unroll
            for (int r = 0; r < 8; ++r) {
                float xv = xq[r][v];
#pragma unroll
                for (int c = 0; c < 8; ++c)
                    pacc[r][c] = fmaf(xv, ps[c], pacc[r][c]);
            }
        }
    }

    // 4-lane jw reduction on VALU pipe (DPP)
#pragma unroll
    for (int r = 0; r < 8; ++r)
#pragma unroll
        for (int c = 0; c < 8; ++c) pacc[r][c] = qsum(pacc[r][c]);

    if (jw == 0) {
#pragma unroll
        for (int r = 0; r < 8; ++r) {
            int s = sq + 8 * r;
            float* hq = &hp[(w8 * SS + s) * 20 + ih * 8];
            *(float4*)(hq)     = make_float4(pacc[r][0], pacc[r][1], pacc[r][2], pacc[r][3]);
            *(float4*)(hq + 4) = make_float4(pacc[r][4], pacc[r][5], pacc[r][6], pacc[r][7]);
        }
    }
    __syncthreads();

    // ---- final: sum 8 wave-partials, scale, sigmoid, store ----
    {
        int i = t & 15, sb = t >> 4;
        float vi = s_inv[i];
#pragma unroll
        for (int rr = 0; rr < 2; ++rr) {
            int s = sb + 32 * rr;
            float h = 0.f;
#pragma unroll
            for (int ww = 0; ww < 8; ++ww) h += hp[(ww * SS + s) * 20 + i];
            h *= vi;
            out0[((size_t)(b * SS + s)) * NN + i0 + i] = 1.0f / (1.0f + __expf(-h));
        }
    }
}

extern "C" void kernel_launch(void* const* d_in, const int* in_sizes, int n_in,
                              void* d_out, int out_size, void* d_ws, size_t ws_size,
                              hipStream_t stream) {
    const float* x   = (const float*)d_in[0];
    const float* W   = (const float*)d_in[1];
    const float* b_w = (const float*)d_in[2];
    const float* Wa  = (const float*)d_in[3];

    float* out0 = (float*)d_out;                         // (B,S,N)
    float* out1 = (float*)d_out + (size_t)BB * SS * NN;  // (B,N,N)

    float* tip = (float*)d_ws;                                   // (B,E,N) fp32
    unsigned short* tjb = (unsigned short*)(tip + (size_t)BB * EE * NN);  // (B,E,N) bf16
    float* cip = (float*)(tjb + (size_t)BB * EE * NN);           // (B,N)
    float* djp = cip + (size_t)BB * NN;                          // (B,N)

    proj_kernel<<<BB * (NN / 8), 128, 0, stream>>>(x, W, b_w, Wa, tip, tjb, cip, djp);
    attn_kernel<<<BB * (NN / IT), 512, 0, stream>>>(x, tip, tjb, cip, djp, Wa, out0, out1);
}